// Round 4
// baseline (14912.424 us; speedup 1.0000x reference)
//
#include <hip/hip_runtime.h>
#include <hip/hip_bf16.h>
#include <stdint.h>

#define T_NUM 1024
#define H_DIM 2048
#define E_NUM 16
#define TOPK 4
#define I_DIM 1408
#define SHI_DIM 2816

typedef __attribute__((ext_vector_type(4))) float f32x4;
typedef __attribute__((ext_vector_type(8))) short bf16x8;
typedef __attribute__((ext_vector_type(4))) short s16x4;

static __device__ __forceinline__ short f2bf(float f) {
    __hip_bfloat16 h = __float2bfloat16(f);
    return __builtin_bit_cast(short, h);
}
static __device__ __forceinline__ float bf2f(short s) {
    return __bfloat162float(__builtin_bit_cast(__hip_bfloat16, s));
}

static __device__ __forceinline__ void gll16(const short* g, const short* l) {
    __builtin_amdgcn_global_load_lds(
        (const __attribute__((address_space(1))) void*)g,
        (__attribute__((address_space(3))) void*)l, 16, 0, 0);
}

// ---------------- router: fp32 logits -> softmax -> top4 (+ x -> bf16) ------
__global__ void router_kernel(const float* __restrict__ x, const float* __restrict__ wgate,
                              int* __restrict__ top_e, float* __restrict__ top_w,
                              short* __restrict__ xb) {
    const int t = blockIdx.x;
    const int tid = threadIdx.x;       // 256 threads
    __shared__ float xsh[H_DIM];
    const float* xr = x + (size_t)t * H_DIM;
    for (int h = tid; h < H_DIM; h += 256) xsh[h] = xr[h];
    __syncthreads();

    {   // bf16 copy of x
        short v[8];
        #pragma unroll
        for (int i = 0; i < 8; ++i) v[i] = f2bf(xsh[tid * 8 + i]);
        *reinterpret_cast<bf16x8*>(xb + (size_t)t * H_DIM + tid * 8) = *(bf16x8*)v;
    }

    const int e = tid >> 4;            // 0..15
    const int j = tid & 15;
    const float* wr = wgate + (size_t)e * H_DIM;
    float acc = 0.f;
    for (int h = j; h < H_DIM; h += 16) acc += xsh[h] * wr[h];
    #pragma unroll
    for (int m = 8; m >= 1; m >>= 1) acc += __shfl_down(acc, m, 16);

    __shared__ float logits[E_NUM];
    if (j == 0) logits[e] = acc;
    __syncthreads();

    if (tid == 0) {
        float mx = logits[0];
        #pragma unroll
        for (int i = 1; i < E_NUM; ++i) mx = fmaxf(mx, logits[i]);
        float p[E_NUM]; float s = 0.f;
        #pragma unroll
        for (int i = 0; i < E_NUM; ++i) { p[i] = expf(logits[i] - mx); s += p[i]; }
        const float inv = 1.f / s;
        #pragma unroll
        for (int i = 0; i < E_NUM; ++i) p[i] *= inv;
        for (int k = 0; k < TOPK; ++k) {
            float best = -1.f; int bi = 0;
            #pragma unroll
            for (int i = 0; i < E_NUM; ++i) if (p[i] > best) { best = p[i]; bi = i; }
            top_e[t * TOPK + k] = bi;
            top_w[t * TOPK + k] = best;
            p[bi] = -2.f;
        }
    }
}

// ------- stable bucket sort of 4096 slots by expert (deterministic) -------
__global__ void perm_kernel(const int* __restrict__ top_e,
                            int* __restrict__ offs, int* __restrict__ perm) {
    __shared__ int cnt[256][E_NUM];
    __shared__ int base[E_NUM];
    const int tid = threadIdx.x;
    int c[E_NUM];
    #pragma unroll
    for (int i = 0; i < E_NUM; ++i) c[i] = 0;
    for (int s = tid * 16; s < tid * 16 + 16; ++s) c[top_e[s]]++;
    #pragma unroll
    for (int i = 0; i < E_NUM; ++i) cnt[tid][i] = c[i];
    __syncthreads();
    if (tid < E_NUM) {
        int run = 0;
        for (int b = 0; b < 256; ++b) { int v = cnt[b][tid]; cnt[b][tid] = run; run += v; }
        base[tid] = run;
    }
    __syncthreads();
    if (tid == 0) {
        int run = 0;
        for (int e2 = 0; e2 < E_NUM; ++e2) { int v = base[e2]; base[e2] = run; offs[e2] = run; run += v; }
        offs[E_NUM] = run;
    }
    __syncthreads();
    int run[E_NUM];
    #pragma unroll
    for (int i = 0; i < E_NUM; ++i) run[i] = base[i] + cnt[tid][i];
    for (int s = tid * 16; s < tid * 16 + 16; ++s) {
        int e2 = top_e[s];
        perm[run[e2]++] = s;
    }
}

// ------- SwiGLU combine: act = silu(g) * u  (bf16 elementwise) -------
__global__ void swiglu_kernel(const short* __restrict__ g, const short* __restrict__ u,
                              short* __restrict__ act, int n8) {
    const int i = blockIdx.x * 256 + threadIdx.x;
    if (i >= n8) return;
    bf16x8 gv = *reinterpret_cast<const bf16x8*>(g + (size_t)i * 8);
    bf16x8 uv = *reinterpret_cast<const bf16x8*>(u + (size_t)i * 8);
    short o[8];
    #pragma unroll
    for (int j = 0; j < 8; ++j) {
        float gf = bf2f(gv[j]);
        float uf = bf2f(uv[j]);
        o[j] = f2bf(gf / (1.f + __expf(-gf)) * uf);
    }
    *reinterpret_cast<bf16x8*>(act + (size_t)i * 8) = *(bf16x8*)o;
}

// ---------------- GEMM: A bf16 k-contig (gll16, 3-buf, depth-2 prefetch);
//                  B f32 [K][N] native (reg-stage convert, 2-buf KP=40) ------
// MODE 0: routed gate|up : A=xb gathered; nt<nsplit ? wg[e]->Out1 : wu[e]->Out2 (bf16)
// MODE 1: shared gate|up : A=xb dense;    nt<nsplit ? sg->Out1 : su->Out2 (bf16)
// MODE 2: routed down    : A=act_r gathered; B=wd[e]; atomicAdd f32 Out1[token]*w
// MODE 3: shared down    : A=act_s dense;    B=sd;    store f32 Out1[row]
template<int MODE>
__global__ __launch_bounds__(256, 3) void gemm2(
    const short* __restrict__ A, int lda, int Kdim,
    const float* __restrict__ B1g, const float* __restrict__ B2g, int ldb,
    void* __restrict__ Out1v, void* __restrict__ Out2v, int ldo,
    const int* __restrict__ perm, const int* __restrict__ offs,
    const float* __restrict__ top_w, int nmt, int nnt, int nsplit)
{
    __shared__ __align__(16) short As[3][128 * 32];   // 24 KB, linear+XOR (gll16)
    __shared__ __align__(16) short Bs[2][128 * 40];   // 20 KB, [n][k] KP=40
    __shared__ int   rows_a[128];
    __shared__ int   rows_o[128];
    __shared__ float w_m[128];

    const int tid = threadIdx.x;

    // bijective XCD swizzle, mt innermost
    int wgid = blockIdx.x;
    {
        const int nwg = gridDim.x;
        const int qq = nwg >> 3, rr = nwg & 7;
        const int xcd = wgid & 7, lin = wgid >> 3;
        wgid = (xcd < rr ? xcd * (qq + 1) : rr * (qq + 1) + (xcd - rr) * qq) + lin;
    }
    const int mt  = wgid % nmt;
    const int ntt = (wgid / nmt) % nnt;
    const int e   = wgid / (nmt * nnt);

    int off = 0, cnt = T_NUM;
    const float* B1 = B1g;
    const float* B2 = B2g;
    if constexpr (MODE == 0) {
        off = offs[e]; cnt = offs[e + 1] - off;
        if (mt * 128 >= cnt) return;
        B1 = B1g + (size_t)e * H_DIM * I_DIM;
        B2 = B2g + (size_t)e * H_DIM * I_DIM;
    }
    if constexpr (MODE == 2) {
        off = offs[e]; cnt = offs[e + 1] - off;
        if (mt * 128 >= cnt) return;
        B1 = B1g + (size_t)e * I_DIM * H_DIM;
    }
    const float* Bsel = (ntt < nsplit) ? B1 : B2;
    const int ncol = (ntt % nsplit) * 128;

    if (tid < 128) {
        const int gm = mt * 128 + tid;
        if constexpr (MODE == 0) {
            int s = perm[off + (gm < cnt ? gm : cnt - 1)];
            rows_a[tid] = s >> 2; rows_o[tid] = s; w_m[tid] = 1.f;
        } else if constexpr (MODE == 2) {
            int s = perm[off + (gm < cnt ? gm : cnt - 1)];
            rows_a[tid] = s; rows_o[tid] = s >> 2; w_m[tid] = top_w[s];
        } else {
            rows_a[tid] = gm; rows_o[tid] = gm; w_m[tid] = 1.f;
        }
    }
    __syncthreads();   // before pipeline starts; full drain OK here

    int raReg[2];
    #pragma unroll
    for (int it = 0; it < 2; ++it) raReg[it] = rows_a[it * 64 + (tid >> 2)];

    float bReg0[4][4], bReg1[4][4];   // two named B staging sets (static idx)

    auto loadB = [&](float (&br)[4][4], int kt) {
        const int k0 = kt * 32;
        #pragma unroll
        for (int it = 0; it < 4; ++it) {
            const int q = it * 256 + tid;
            const int n = q & 127, kb = (q >> 7) * 4;
            const float* p1 = Bsel + (size_t)(k0 + kb) * ldb + ncol + n;
            #pragma unroll
            for (int dk = 0; dk < 4; ++dk) br[it][dk] = p1[(size_t)dk * ldb];
        }
    };
    auto dswriteB = [&](int bbuf, float (&br)[4][4]) {
        #pragma unroll
        for (int it = 0; it < 4; ++it) {
            const int q = it * 256 + tid;
            const int n = q & 127, kb = (q >> 7) * 4;
            s16x4 v = { f2bf(br[it][0]), f2bf(br[it][1]), f2bf(br[it][2]), f2bf(br[it][3]) };
            *reinterpret_cast<s16x4*>(&Bs[bbuf][n * 40 + kb]) = v;
        }
    };
    auto gllA = [&](int kt) {
        const int abuf = kt % 3;
        const int k0 = kt * 32;
        #pragma unroll
        for (int it = 0; it < 2; ++it) {
            const int q = it * 256 + tid;
            const int m = q >> 2;
            const int c = ((q & 3) ^ ((m >> 1) & 3)) * 8;
            gll16(A + (size_t)raReg[it] * lda + k0 + c, &As[abuf][q * 8]);
        }
    };

    f32x4 acc[4][4];
    #pragma unroll
    for (int i = 0; i < 4; ++i)
        #pragma unroll
        for (int j = 0; j < 4; ++j) acc[i][j] = (f32x4)0.f;

    const int lane = tid & 63;
    const int wr = (tid >> 7), wc = (tid >> 6) & 1;
    const int lrow = lane & 15;
    const int cswz = (((lane >> 4) ^ ((lrow >> 1) & 3)) * 8);  // A read-side XOR
    const int lko = (lane >> 4) * 8;                           // B read offset

    auto compute = [&](int abuf, int bbuf) {
        bf16x8 af[4];
        #pragma unroll
        for (int mi = 0; mi < 4; ++mi)
            af[mi] = *reinterpret_cast<const bf16x8*>(&As[abuf][(wr * 64 + mi * 16 + lrow) * 32 + cswz]);
        #pragma unroll
        for (int ni = 0; ni < 4; ++ni) {
            bf16x8 bfr = *reinterpret_cast<const bf16x8*>(&Bs[bbuf][(wc * 64 + ni * 16 + lrow) * 40 + lko]);
            #pragma unroll
            for (int mi = 0; mi < 4; ++mi)
                acc[mi][ni] = __builtin_amdgcn_mfma_f32_16x16x32_bf16(af[mi], bfr, acc[mi][ni], 0, 0, 0);
        }
    };

    const int NK = Kdim / 32;   // even for all our K (64, 44, 88)

    // ---- prologue: 2 tiles in flight ----
    loadB(bReg0, 0); gllA(0);
    loadB(bReg1, 1); gllA(1);
    asm volatile("s_waitcnt vmcnt(18)" ::: "memory");   // tile0 (B16+A2) done
    dswriteB(0, bReg0);
    asm volatile("s_waitcnt lgkmcnt(0)" ::: "memory");
    __builtin_amdgcn_s_barrier();

    for (int kt = 0; kt < NK; kt += 2) {
        // ---- even step: compute tile kt (Abuf kt%3, Bbuf 0); bReg1 holds B(kt+1)
        if (kt + 2 < NK) {
            loadB(bReg0, kt + 2); gllA(kt + 2);
            asm volatile("s_waitcnt vmcnt(18)" ::: "memory");   // tile kt+1 done
        } else {
            asm volatile("s_waitcnt vmcnt(0)" ::: "memory");
        }
        dswriteB(1, bReg1);
        compute(kt % 3, 0);
        asm volatile("s_waitcnt lgkmcnt(0)" ::: "memory");
        __builtin_amdgcn_s_barrier();

        // ---- odd step: compute tile kt+1 (Abuf (kt+1)%3, Bbuf 1); bReg0 holds B(kt+2)
        if (kt + 3 < NK) {
            loadB(bReg1, kt + 3); gllA(kt + 3);
            asm volatile("s_waitcnt vmcnt(18)" ::: "memory");   // tile kt+2 done
        } else {
            asm volatile("s_waitcnt vmcnt(0)" ::: "memory");
        }
        if (kt + 2 < NK) dswriteB(0, bReg0);
        compute((kt + 1) % 3, 1);
        if (kt + 3 < NK || kt + 2 < NK) {
            asm volatile("s_waitcnt lgkmcnt(0)" ::: "memory");
            __builtin_amdgcn_s_barrier();
        }
    }

    // ---- epilogue ----
    #pragma unroll
    for (int mi = 0; mi < 4; ++mi) {
        #pragma unroll
        for (int j = 0; j < 4; ++j) {
            const int ml = wr * 64 + mi * 16 + (lane >> 4) * 4 + j;
            const int gm = mt * 128 + ml;
            if constexpr (MODE == 0 || MODE == 2) { if (gm >= cnt) continue; }
            const int orow = (MODE == 0 || MODE == 2) ? rows_o[ml] : gm;
            const float wsc = w_m[ml];
            #pragma unroll
            for (int ni = 0; ni < 4; ++ni) {
                const int n = ncol + wc * 64 + ni * 16 + (lane & 15);
                const float v = acc[mi][ni][j];
                if constexpr (MODE == 0 || MODE == 1) {
                    short* o = (short*)((ntt < nsplit) ? Out1v : Out2v);
                    o[(size_t)orow * ldo + n] = f2bf(v);
                } else if constexpr (MODE == 2) {
                    atomicAdd(&((float*)Out1v)[(size_t)orow * ldo + n], v * wsc);
                } else {
                    ((float*)Out1v)[(size_t)orow * ldo + n] = v;
                }
            }
        }
    }
}

extern "C" void kernel_launch(void* const* d_in, const int* in_sizes, int n_in,
                              void* d_out, int out_size, void* d_ws, size_t ws_size,
                              hipStream_t stream) {
    const float* x     = (const float*)d_in[0];
    const float* wgate = (const float*)d_in[1];
    const float* wg    = (const float*)d_in[2];
    const float* wu    = (const float*)d_in[3];
    const float* wd    = (const float*)d_in[4];
    const float* sg    = (const float*)d_in[5];
    const float* su    = (const float*)d_in[6];
    const float* sd    = (const float*)d_in[7];
    float* out = (float*)d_out;

    uintptr_t p = (uintptr_t)d_ws;
    auto alloc = [&](size_t bytes) {
        p = (p + 255) & ~(uintptr_t)255;
        void* r = (void*)p; p += bytes; return r;
    };
    int*   top_e = (int*)alloc((size_t)T_NUM * TOPK * sizeof(int));
    float* top_w = (float*)alloc((size_t)T_NUM * TOPK * sizeof(float));
    int*   offs  = (int*)alloc((E_NUM + 1) * sizeof(int));
    int*   perm  = (int*)alloc((size_t)T_NUM * TOPK * sizeof(int));
    short* xb    = (short*)alloc((size_t)T_NUM * H_DIM * 2);
    short* g_r   = (short*)alloc((size_t)T_NUM * TOPK * I_DIM * 2);
    short* u_r   = (short*)alloc((size_t)T_NUM * TOPK * I_DIM * 2);
    short* act_r = (short*)alloc((size_t)T_NUM * TOPK * I_DIM * 2);
    short* g_s   = (short*)alloc((size_t)T_NUM * SHI_DIM * 2);
    short* u_s   = (short*)alloc((size_t)T_NUM * SHI_DIM * 2);
    short* act_s = (short*)alloc((size_t)T_NUM * SHI_DIM * 2);

    router_kernel<<<T_NUM, 256, 0, stream>>>(x, wgate, top_e, top_w, xb);
    perm_kernel<<<1, 256, 0, stream>>>(top_e, offs, perm);

    const int nmtT = T_NUM / 128;   // 8
    const int nnI  = I_DIM / 128;   // 11
    const int nnH  = H_DIM / 128;   // 16
    const int nnS  = SHI_DIM / 128; // 22

    // shared gate|up (one dispatch, nt-split): grid 8 * 44
    gemm2<1><<<nmtT * (2 * nnS), 256, 0, stream>>>(
        xb, H_DIM, H_DIM, sg, su, SHI_DIM, g_s, u_s, SHI_DIM,
        nullptr, nullptr, nullptr, nmtT, 2 * nnS, nnS);
    swiglu_kernel<<<(T_NUM * SHI_DIM / 8 + 255) / 256, 256, 0, stream>>>(
        g_s, u_s, act_s, T_NUM * SHI_DIM / 8);
    // shared down: plain stores initialize all of out. grid 8 * 16
    gemm2<3><<<nmtT * nnH, 256, 0, stream>>>(
        act_s, SHI_DIM, SHI_DIM, sd, nullptr, H_DIM, out, nullptr, H_DIM,
        nullptr, nullptr, nullptr, nmtT, nnH, nnH);

    // routed gate|up per expert (one dispatch): grid 8 * 22 * 16
    gemm2<0><<<nmtT * (2 * nnI) * E_NUM, 256, 0, stream>>>(
        xb, H_DIM, H_DIM, wg, wu, I_DIM, g_r, u_r, I_DIM,
        perm, offs, nullptr, nmtT, 2 * nnI, nnI);
    swiglu_kernel<<<(T_NUM * TOPK * I_DIM / 8 + 255) / 256, 256, 0, stream>>>(
        g_r, u_r, act_r, T_NUM * TOPK * I_DIM / 8);
    // routed down per expert: out[token] += w * (act_r[slot] @ wd[e]). grid 8 * 16 * 16
    gemm2<2><<<nmtT * nnH * E_NUM, 256, 0, stream>>>(
        act_r, I_DIM, I_DIM, wd, nullptr, H_DIM, out, nullptr, H_DIM,
        perm, offs, top_w, nmtT, nnH, nnH);
}

// Round 5
// 579.213 us; speedup vs baseline: 25.7460x; 25.7460x over previous
//
#include <hip/hip_runtime.h>
#include <hip/hip_bf16.h>
#include <stdint.h>

#define T_NUM 1024
#define H_DIM 2048
#define E_NUM 16
#define TOPK 4
#define I_DIM 1408
#define SHI_DIM 2816

typedef __attribute__((ext_vector_type(4))) float f32x4;
typedef __attribute__((ext_vector_type(8))) short bf16x8;
typedef __attribute__((ext_vector_type(4))) short s16x4;

static __device__ __forceinline__ short f2bf(float f) {
    __hip_bfloat16 h = __float2bfloat16(f);
    return __builtin_bit_cast(short, h);
}
static __device__ __forceinline__ float bf2f(short s) {
    return __bfloat162float(__builtin_bit_cast(__hip_bfloat16, s));
}

// ---------------- router: fp32 logits -> softmax -> top4 (+ x -> bf16) ------
__global__ void router_kernel(const float* __restrict__ x, const float* __restrict__ wgate,
                              int* __restrict__ top_e, float* __restrict__ top_w,
                              short* __restrict__ xb) {
    const int t = blockIdx.x;
    const int tid = threadIdx.x;       // 256 threads
    __shared__ float xsh[H_DIM];
    const float* xr = x + (size_t)t * H_DIM;
    for (int h = tid; h < H_DIM; h += 256) xsh[h] = xr[h];
    __syncthreads();

    {   // bf16 copy of x
        short v[8];
        #pragma unroll
        for (int i = 0; i < 8; ++i) v[i] = f2bf(xsh[tid * 8 + i]);
        *reinterpret_cast<bf16x8*>(xb + (size_t)t * H_DIM + tid * 8) = *(bf16x8*)v;
    }

    const int e = tid >> 4;            // 0..15
    const int j = tid & 15;
    const float* wr = wgate + (size_t)e * H_DIM;
    float acc = 0.f;
    for (int h = j; h < H_DIM; h += 16) acc += xsh[h] * wr[h];
    #pragma unroll
    for (int m = 8; m >= 1; m >>= 1) acc += __shfl_down(acc, m, 16);

    __shared__ float logits[E_NUM];
    if (j == 0) logits[e] = acc;
    __syncthreads();

    if (tid == 0) {
        float mx = logits[0];
        #pragma unroll
        for (int i = 1; i < E_NUM; ++i) mx = fmaxf(mx, logits[i]);
        float p[E_NUM]; float s = 0.f;
        #pragma unroll
        for (int i = 0; i < E_NUM; ++i) { p[i] = expf(logits[i] - mx); s += p[i]; }
        const float inv = 1.f / s;
        #pragma unroll
        for (int i = 0; i < E_NUM; ++i) p[i] *= inv;
        for (int k = 0; k < TOPK; ++k) {
            float best = -1.f; int bi = 0;
            #pragma unroll
            for (int i = 0; i < E_NUM; ++i) if (p[i] > best) { best = p[i]; bi = i; }
            top_e[t * TOPK + k] = bi;
            top_w[t * TOPK + k] = best;
            p[bi] = -2.f;
        }
    }
}

// ------- stable bucket sort of 4096 slots by expert (deterministic) -------
__global__ void perm_kernel(const int* __restrict__ top_e,
                            int* __restrict__ offs, int* __restrict__ perm) {
    __shared__ int cnt[256][E_NUM];
    __shared__ int base[E_NUM];
    const int tid = threadIdx.x;
    int c[E_NUM];
    #pragma unroll
    for (int i = 0; i < E_NUM; ++i) c[i] = 0;
    for (int s = tid * 16; s < tid * 16 + 16; ++s) c[top_e[s]]++;
    #pragma unroll
    for (int i = 0; i < E_NUM; ++i) cnt[tid][i] = c[i];
    __syncthreads();
    if (tid < E_NUM) {
        int run = 0;
        for (int b = 0; b < 256; ++b) { int v = cnt[b][tid]; cnt[b][tid] = run; run += v; }
        base[tid] = run;
    }
    __syncthreads();
    if (tid == 0) {
        int run = 0;
        for (int e2 = 0; e2 < E_NUM; ++e2) { int v = base[e2]; base[e2] = run; offs[e2] = run; run += v; }
        offs[E_NUM] = run;
    }
    __syncthreads();
    int run[E_NUM];
    #pragma unroll
    for (int i = 0; i < E_NUM; ++i) run[i] = base[i] + cnt[tid][i];
    for (int s = tid * 16; s < tid * 16 + 16; ++s) {
        int e2 = top_e[s];
        perm[run[e2]++] = s;
    }
}

// ------- SwiGLU combine: act = silu(g) * u  (bf16 elementwise) -------
__global__ void swiglu_kernel(const short* __restrict__ g, const short* __restrict__ u,
                              short* __restrict__ act, int n8) {
    const int i = blockIdx.x * 256 + threadIdx.x;
    if (i >= n8) return;
    bf16x8 gv = *reinterpret_cast<const bf16x8*>(g + (size_t)i * 8);
    bf16x8 uv = *reinterpret_cast<const bf16x8*>(u + (size_t)i * 8);
    short o[8];
    #pragma unroll
    for (int j = 0; j < 8; ++j) {
        float gf = bf2f(gv[j]);
        float uf = bf2f(uv[j]);
        o[j] = f2bf(gf / (1.f + __expf(-gf)) * uf);
    }
    *reinterpret_cast<bf16x8*>(act + (size_t)i * 8) = *(bf16x8*)o;
}

// ---------------- GEMM (R1 structure, NB=1, 3 blocks/CU) ----------------
// A: bf16 [rows][K] k-contig. B: f32 [K][N] native (inline convert).
// MODE 0: routed gate|up : A=xb gathered; ntt<nsplit ? wg[e]->Out1 : wu[e]->Out2 (bf16)
// MODE 1: shared gate|up : A=xb dense;    ntt<nsplit ? sg->Out1 : su->Out2 (bf16)
// MODE 2: routed down    : A=act_r gathered; B=wd[e]; atomicAdd f32 Out1[token]*w
// MODE 3: shared down    : A=act_s dense;    B=sd;    store f32 Out1[row]
template<int MODE>
__global__ __launch_bounds__(256, 3) void gemm_nb1(
    const short* __restrict__ A, int lda, int Kdim,
    const float* __restrict__ B1g, const float* __restrict__ B2g, int ldb,
    void* __restrict__ Out1v, void* __restrict__ Out2v, int ldo,
    const int* __restrict__ perm, const int* __restrict__ offs,
    const float* __restrict__ top_w, int nmt, int nnt, int nsplit)
{
    constexpr int KP = 40;
    __shared__ short As[2][128 * KP];     // 20 KB
    __shared__ short Bs[2][128 * KP];     // 20 KB
    __shared__ int   rows_a[128];
    __shared__ int   rows_o[128];
    __shared__ float w_m[128];

    const int tid = threadIdx.x;

    // bijective XCD swizzle, mt innermost (mt-blocks sharing a B-strip -> same XCD L2)
    int wgid = blockIdx.x;
    {
        const int nwg = gridDim.x;
        const int qq = nwg >> 3, rr = nwg & 7;
        const int xcd = wgid & 7, lin = wgid >> 3;
        wgid = (xcd < rr ? xcd * (qq + 1) : rr * (qq + 1) + (xcd - rr) * qq) + lin;
    }
    const int mt  = wgid % nmt;
    const int ntt = (wgid / nmt) % nnt;
    const int e   = wgid / (nmt * nnt);

    int off = 0, cnt = T_NUM;
    const float* B1 = B1g;
    const float* B2 = B2g;
    if constexpr (MODE == 0) {
        off = offs[e]; cnt = offs[e + 1] - off;
        if (mt * 128 >= cnt) return;
        B1 = B1g + (size_t)e * H_DIM * I_DIM;
        B2 = B2g + (size_t)e * H_DIM * I_DIM;
    }
    if constexpr (MODE == 2) {
        off = offs[e]; cnt = offs[e + 1] - off;
        if (mt * 128 >= cnt) return;
        B1 = B1g + (size_t)e * I_DIM * H_DIM;
    }
    const float* Bsel = (ntt < nsplit) ? B1 : B2;
    const int ncol = (ntt % nsplit) * 128;

    if (tid < 128) {
        const int gm = mt * 128 + tid;
        if constexpr (MODE == 0) {
            int s = perm[off + (gm < cnt ? gm : cnt - 1)];
            rows_a[tid] = s >> 2; rows_o[tid] = s; w_m[tid] = 1.f;
        } else if constexpr (MODE == 2) {
            int s = perm[off + (gm < cnt ? gm : cnt - 1)];
            rows_a[tid] = s; rows_o[tid] = s >> 2; w_m[tid] = top_w[s];
        } else {
            rows_a[tid] = gm; rows_o[tid] = gm; w_m[tid] = 1.f;
        }
    }
    __syncthreads();

    // A row indices in registers (2 rows per thread: m = it*64 + (tid>>2))
    int raReg[2];
    #pragma unroll
    for (int it = 0; it < 2; ++it) raReg[it] = rows_a[it * 64 + (tid >> 2)];

    bf16x8 aReg[2];          // A staging (bf16, 16 B/thread-iter)
    float  bReg[4][4];       // B staging (f32 strided, converted on swrite)

    auto gload = [&](int kt) {
        const int k0 = kt * 32;
        #pragma unroll
        for (int it = 0; it < 2; ++it) {
            const int q = it * 256 + tid;
            const int ko = (q & 3) * 8;
            aReg[it] = *reinterpret_cast<const bf16x8*>(A + (size_t)raReg[it] * lda + k0 + ko);
        }
        #pragma unroll
        for (int it = 0; it < 4; ++it) {
            const int q = it * 256 + tid;
            const int n = q & 127, kb = (q >> 7) * 4;
            const float* p1 = Bsel + (size_t)(k0 + kb) * ldb + ncol + n;
            #pragma unroll
            for (int dk = 0; dk < 4; ++dk) bReg[it][dk] = p1[(size_t)dk * ldb];
        }
    };

    auto swrite = [&](int buf) {
        #pragma unroll
        for (int it = 0; it < 2; ++it) {
            const int q = it * 256 + tid;
            const int m = q >> 2, ko = (q & 3) * 8;
            *reinterpret_cast<bf16x8*>(&As[buf][m * KP + ko]) = aReg[it];
        }
        #pragma unroll
        for (int it = 0; it < 4; ++it) {
            const int q = it * 256 + tid;
            const int n = q & 127, kb = (q >> 7) * 4;
            s16x4 v = { f2bf(bReg[it][0]), f2bf(bReg[it][1]), f2bf(bReg[it][2]), f2bf(bReg[it][3]) };
            *reinterpret_cast<s16x4*>(&Bs[buf][n * KP + kb]) = v;
        }
    };

    f32x4 acc[4][4];
    #pragma unroll
    for (int i = 0; i < 4; ++i)
        #pragma unroll
        for (int j = 0; j < 4; ++j) acc[i][j] = (f32x4)0.f;

    const int lane = tid & 63;
    const int wr = (tid >> 7), wc = (tid >> 6) & 1;
    const int lrow = lane & 15;
    const int lko = (lane >> 4) * 8;

    auto compute = [&](int buf) {
        bf16x8 af[4];
        #pragma unroll
        for (int mi = 0; mi < 4; ++mi)
            af[mi] = *reinterpret_cast<const bf16x8*>(&As[buf][(wr * 64 + mi * 16 + lrow) * KP + lko]);
        #pragma unroll
        for (int ni = 0; ni < 4; ++ni) {
            bf16x8 bfr = *reinterpret_cast<const bf16x8*>(&Bs[buf][(wc * 64 + ni * 16 + lrow) * KP + lko]);
            #pragma unroll
            for (int mi = 0; mi < 4; ++mi)
                acc[mi][ni] = __builtin_amdgcn_mfma_f32_16x16x32_bf16(af[mi], bfr, acc[mi][ni], 0, 0, 0);
        }
    };

    const int NK = Kdim / 32;
    gload(0);
    int cur = 0;
    for (int kt = 0; kt < NK; ++kt) {
        swrite(cur);
        __syncthreads();
        if (kt + 1 < NK) gload(kt + 1);
        compute(cur);
        cur ^= 1;
    }

    // epilogue
    #pragma unroll
    for (int mi = 0; mi < 4; ++mi) {
        #pragma unroll
        for (int j = 0; j < 4; ++j) {
            const int ml = wr * 64 + mi * 16 + (lane >> 4) * 4 + j;
            const int gm = mt * 128 + ml;
            if constexpr (MODE == 0 || MODE == 2) { if (gm >= cnt) continue; }
            const int orow = (MODE == 0 || MODE == 2) ? rows_o[ml] : gm;
            const float wsc = w_m[ml];
            #pragma unroll
            for (int ni = 0; ni < 4; ++ni) {
                const int n = ncol + wc * 64 + ni * 16 + (lane & 15);
                const float v = acc[mi][ni][j];
                if constexpr (MODE == 0 || MODE == 1) {
                    short* o = (short*)((ntt < nsplit) ? Out1v : Out2v);
                    o[(size_t)orow * ldo + n] = f2bf(v);
                } else if constexpr (MODE == 2) {
                    atomicAdd(&((float*)Out1v)[(size_t)orow * ldo + n], v * wsc);
                } else {
                    ((float*)Out1v)[(size_t)orow * ldo + n] = v;
                }
            }
        }
    }
}

extern "C" void kernel_launch(void* const* d_in, const int* in_sizes, int n_in,
                              void* d_out, int out_size, void* d_ws, size_t ws_size,
                              hipStream_t stream) {
    const float* x     = (const float*)d_in[0];
    const float* wgate = (const float*)d_in[1];
    const float* wg    = (const float*)d_in[2];
    const float* wu    = (const float*)d_in[3];
    const float* wd    = (const float*)d_in[4];
    const float* sg    = (const float*)d_in[5];
    const float* su    = (const float*)d_in[6];
    const float* sd    = (const float*)d_in[7];
    float* out = (float*)d_out;

    uintptr_t p = (uintptr_t)d_ws;
    auto alloc = [&](size_t bytes) {
        p = (p + 255) & ~(uintptr_t)255;
        void* r = (void*)p; p += bytes; return r;
    };
    int*   top_e = (int*)alloc((size_t)T_NUM * TOPK * sizeof(int));
    float* top_w = (float*)alloc((size_t)T_NUM * TOPK * sizeof(float));
    int*   offs  = (int*)alloc((E_NUM + 1) * sizeof(int));
    int*   perm  = (int*)alloc((size_t)T_NUM * TOPK * sizeof(int));
    short* xb    = (short*)alloc((size_t)T_NUM * H_DIM * 2);
    short* g_r   = (short*)alloc((size_t)T_NUM * TOPK * I_DIM * 2);
    short* u_r   = (short*)alloc((size_t)T_NUM * TOPK * I_DIM * 2);
    short* act_r = (short*)alloc((size_t)T_NUM * TOPK * I_DIM * 2);
    short* g_s   = (short*)alloc((size_t)T_NUM * SHI_DIM * 2);
    short* u_s   = (short*)alloc((size_t)T_NUM * SHI_DIM * 2);
    short* act_s = (short*)alloc((size_t)T_NUM * SHI_DIM * 2);

    router_kernel<<<T_NUM, 256, 0, stream>>>(x, wgate, top_e, top_w, xb);
    perm_kernel<<<1, 256, 0, stream>>>(top_e, offs, perm);

    const int nmtT = T_NUM / 128;   // 8
    const int nnI  = I_DIM / 128;   // 11
    const int nnH  = H_DIM / 128;   // 16
    const int nnS  = SHI_DIM / 128; // 22

    // shared gate|up (one dispatch, nt-split): grid 8 * 44
    gemm_nb1<1><<<nmtT * (2 * nnS), 256, 0, stream>>>(
        xb, H_DIM, H_DIM, sg, su, SHI_DIM, g_s, u_s, SHI_DIM,
        nullptr, nullptr, nullptr, nmtT, 2 * nnS, nnS);
    swiglu_kernel<<<(T_NUM * SHI_DIM / 8 + 255) / 256, 256, 0, stream>>>(
        g_s, u_s, act_s, T_NUM * SHI_DIM / 8);
    // shared down: plain stores initialize all of out. grid 8 * 16
    gemm_nb1<3><<<nmtT * nnH, 256, 0, stream>>>(
        act_s, SHI_DIM, SHI_DIM, sd, nullptr, H_DIM, out, nullptr, H_DIM,
        nullptr, nullptr, nullptr, nmtT, nnH, nnH);

    // routed gate|up per expert (one dispatch): grid 8 * 22 * 16
    gemm_nb1<0><<<nmtT * (2 * nnI) * E_NUM, 256, 0, stream>>>(
        xb, H_DIM, H_DIM, wg, wu, I_DIM, g_r, u_r, I_DIM,
        perm, offs, nullptr, nmtT, 2 * nnI, nnI);
    swiglu_kernel<<<(T_NUM * TOPK * I_DIM / 8 + 255) / 256, 256, 0, stream>>>(
        g_r, u_r, act_r, T_NUM * TOPK * I_DIM / 8);
    // routed down per expert: out[token] += w * (act_r[slot] @ wd[e]). grid 8 * 16 * 16
    gemm_nb1<2><<<nmtT * nnH * E_NUM, 256, 0, stream>>>(
        act_r, I_DIM, I_DIM, wd, nullptr, H_DIM, out, nullptr, H_DIM,
        perm, offs, top_w, nmtT, nnH, nnH);
}